// Round 1
// baseline (429.978 us; speedup 1.0000x reference)
//
#include <hip/hip_runtime.h>
#include <stdint.h>

typedef __attribute__((ext_vector_type(8))) short bf8_t;
typedef __attribute__((ext_vector_type(4))) float f4_t;

#define D_MODEL 1024
#define SEQ 2048
#define NB 4
#define NH 16
#define HD 64
#define MROWS (NB * SEQ)

__device__ __forceinline__ uint16_t f2bf(float f) {
  uint32_t u = __builtin_bit_cast(uint32_t, f);
  u += 0x7FFFu + ((u >> 16) & 1u);
  return (uint16_t)(u >> 16);
}

__device__ __forceinline__ void gload16(const void* g, void* l) {
  __builtin_amdgcn_global_load_lds(
      (const __attribute__((address_space(1))) void*)g,
      (__attribute__((address_space(3))) void*)l, 16, 0, 0);
}

// ---- fp32 -> bf16 elementwise (vectorized) ----
__global__ void k_cvt(const float* __restrict__ in, uint16_t* __restrict__ out, int n4) {
  int i = blockIdx.x * blockDim.x + threadIdx.x;
  if (i >= n4) return;
  float4 v = ((const float4*)in)[i];
  ushort4 o;
  o.x = f2bf(v.x); o.y = f2bf(v.y); o.z = f2bf(v.z); o.w = f2bf(v.w);
  ((ushort4*)out)[i] = o;
}

// ---- transpose+convert: in [K][N] fp32 -> out [N][K] bf16 ----
__global__ void k_tcvt(const float* __restrict__ in, uint16_t* __restrict__ out, int K, int N) {
  __shared__ float tile[32][33];
  int nb = blockIdx.x * 32, kb = blockIdx.y * 32;
  int tx = threadIdx.x & 31, ty = threadIdx.x >> 5;
#pragma unroll
  for (int i = 0; i < 4; ++i)
    tile[ty + i * 8][tx] = in[(size_t)(kb + ty + i * 8) * N + nb + tx];
  __syncthreads();
#pragma unroll
  for (int i = 0; i < 4; ++i)
    out[(size_t)(nb + ty + i * 8) * K + kb + tx] = f2bf(tile[tx][ty + i * 8]);
}

// ---- shared GEMM mainloop: C[128x128] = A[128xK] * Bt[128xK]^T, K=1024, BK=64 ----
// LDS rows are 128B; global source granule is pre-swizzled (c ^ (r&7)) so that
// swizzled ds_read_b128 fragment loads are bank-conflict-free (rule #21).
__device__ __forceinline__ void gemm_mainloop(const uint16_t* __restrict__ A,
                                              const uint16_t* __restrict__ Bt,
                                              int mBase, int nBase, f4_t acc[4][4],
                                              uint16_t* As, uint16_t* Bs) {
  const int t = threadIdx.x;
  const int lane = t & 63;
  const int wm = (t >> 6) >> 1, wn = (t >> 6) & 1;
  for (int ks = 0; ks < D_MODEL / 64; ++ks) {
#pragma unroll
    for (int iss = 0; iss < 4; ++iss) {
      int p = iss * 256 + t;
      int r = p >> 3;
      int c = (p & 7) ^ (r & 7);
      gload16(A + (size_t)(mBase + r) * D_MODEL + ks * 64 + c * 8, As + p * 8);
      gload16(Bt + (size_t)(nBase + r) * D_MODEL + ks * 64 + c * 8, Bs + p * 8);
    }
    __syncthreads();
    bf8_t af[4][2], bfr[4][2];
#pragma unroll
    for (int mi = 0; mi < 4; ++mi) {
      int r = wm * 64 + mi * 16 + (lane & 15);
#pragma unroll
      for (int kx = 0; kx < 2; ++kx) {
        int gl = (lane >> 4) + kx * 4;
        af[mi][kx] = *(const bf8_t*)((const char*)As + r * 128 + ((gl ^ (r & 7)) * 16));
      }
    }
#pragma unroll
    for (int ni = 0; ni < 4; ++ni) {
      int r = wn * 64 + ni * 16 + (lane & 15);
#pragma unroll
      for (int kx = 0; kx < 2; ++kx) {
        int gl = (lane >> 4) + kx * 4;
        bfr[ni][kx] = *(const bf8_t*)((const char*)Bs + r * 128 + ((gl ^ (r & 7)) * 16));
      }
    }
#pragma unroll
    for (int mi = 0; mi < 4; ++mi)
#pragma unroll
      for (int ni = 0; ni < 4; ++ni) {
        acc[mi][ni] = __builtin_amdgcn_mfma_f32_16x16x32_bf16(af[mi][0], bfr[ni][0], acc[mi][ni], 0, 0, 0);
        acc[mi][ni] = __builtin_amdgcn_mfma_f32_16x16x32_bf16(af[mi][1], bfr[ni][1], acc[mi][ni], 0, 0, 0);
      }
    __syncthreads();
  }
}

// ---- QKV GEMM: epilogue routes to Q (scaled 1/8), K, and transposed V ----
__global__ __launch_bounds__(256, 2) void k_gemm_qkv(
    const uint16_t* __restrict__ A, const uint16_t* __restrict__ Bt,
    const float* __restrict__ bias,
    uint16_t* __restrict__ Qb, uint16_t* __restrict__ Kb, uint16_t* __restrict__ VTb) {
  __shared__ uint16_t As[128 * 64];
  __shared__ uint16_t Bs[128 * 64];
  f4_t acc[4][4] = {};
  int mBase = blockIdx.y * 128, nBase = blockIdx.x * 128;
  gemm_mainloop(A, Bt, mBase, nBase, acc, As, Bs);
  const int lane = threadIdx.x & 63;
  const int wm = (threadIdx.x >> 6) >> 1, wn = (threadIdx.x >> 6) & 1;
#pragma unroll
  for (int mi = 0; mi < 4; ++mi)
#pragma unroll
    for (int ni = 0; ni < 4; ++ni)
#pragma unroll
      for (int i = 0; i < 4; ++i) {
        int m = mBase + wm * 64 + mi * 16 + (lane >> 4) * 4 + i;
        int n = nBase + wn * 64 + ni * 16 + (lane & 15);
        float v = acc[mi][ni][i] + bias[n];
        int b = m >> 11, s = m & 2047;
        int which = n >> 10, hn = n & 1023;
        int h = hn >> 6, d = hn & 63;
        size_t bh = (size_t)(b * NH + h);
        if (which == 0)      Qb[(bh * SEQ + s) * HD + d] = f2bf(v * 0.125f);
        else if (which == 1) Kb[(bh * SEQ + s) * HD + d] = f2bf(v);
        else                 VTb[(bh * HD + d) * SEQ + s] = f2bf(v);
      }
}

// ---- proj GEMM: fp32 output + bias ----
__global__ __launch_bounds__(256, 2) void k_gemm_proj(
    const uint16_t* __restrict__ A, const uint16_t* __restrict__ Bt,
    const float* __restrict__ bias, float* __restrict__ out) {
  __shared__ uint16_t As[128 * 64];
  __shared__ uint16_t Bs[128 * 64];
  f4_t acc[4][4] = {};
  int mBase = blockIdx.y * 128, nBase = blockIdx.x * 128;
  gemm_mainloop(A, Bt, mBase, nBase, acc, As, Bs);
  const int lane = threadIdx.x & 63;
  const int wm = (threadIdx.x >> 6) >> 1, wn = (threadIdx.x >> 6) & 1;
#pragma unroll
  for (int mi = 0; mi < 4; ++mi)
#pragma unroll
    for (int ni = 0; ni < 4; ++ni)
#pragma unroll
      for (int i = 0; i < 4; ++i) {
        int m = mBase + wm * 64 + mi * 16 + (lane >> 4) * 4 + i;
        int n = nBase + wn * 64 + ni * 16 + (lane & 15);
        out[(size_t)m * D_MODEL + n] = acc[mi][ni][i] + bias[n];
      }
}

// ---- flash attention, causal. Block: (q-tile of 64, bh). 4 waves x 16 q-rows. ----
__global__ __launch_bounds__(256, 2) void k_attn(
    const uint16_t* __restrict__ Qb, const uint16_t* __restrict__ Kb,
    const uint16_t* __restrict__ VTb, uint16_t* __restrict__ Yb) {
  __shared__ uint16_t Ks[64 * 64];
  __shared__ uint16_t Vs[64 * 64];
  __shared__ uint16_t Ps[4][16 * 64];
  const int t = threadIdx.x, lane = t & 63, wave = t >> 6;
  const int qt = blockIdx.x, bh = blockIdx.y;
  const int b = bh >> 4, h = bh & 15;
  const int qrow0 = qt * 64 + wave * 16;
  // Q fragments hoisted to registers (Q pre-scaled by 1/8 at QKV epilogue)
  const uint16_t* Qrow = Qb + ((size_t)bh * SEQ + qrow0 + (lane & 15)) * HD;
  bf8_t aq[2];
  aq[0] = *(const bf8_t*)(Qrow + (lane >> 4) * 8);
  aq[1] = *(const bf8_t*)(Qrow + (lane >> 4) * 8 + 32);
  float m_i[4], l_i[4];
  f4_t O[4] = {};
#pragma unroll
  for (int i = 0; i < 4; ++i) { m_i[i] = -__builtin_inff(); l_i[i] = 0.f; }
  uint16_t* Pw = Ps[wave];

  for (int kt = 0; kt <= qt; ++kt) {
    __syncthreads();  // all waves done reading previous K/V tiles
#pragma unroll
    for (int iss = 0; iss < 2; ++iss) {
      int p = iss * 256 + t;
      int r = p >> 3, c = (p & 7) ^ (r & 7);
      gload16(Kb + ((size_t)bh * SEQ + kt * 64 + r) * HD + c * 8, Ks + p * 8);
      gload16(VTb + ((size_t)bh * HD + r) * SEQ + kt * 64 + c * 8, Vs + p * 8);
    }
    __syncthreads();
    // S = Q K^T  (16 q-rows x 64 keys, 4 col-fragments)
    f4_t sacc[4] = {};
#pragma unroll
    for (int f = 0; f < 4; ++f) {
      int kr = f * 16 + (lane & 15);
#pragma unroll
      for (int kx = 0; kx < 2; ++kx) {
        int gl = (lane >> 4) + kx * 4;
        bf8_t bk = *(const bf8_t*)((const char*)Ks + kr * 128 + ((gl ^ (kr & 7)) * 16));
        sacc[f] = __builtin_amdgcn_mfma_f32_16x16x32_bf16(aq[kx], bk, sacc[f], 0, 0, 0);
      }
    }
    if (kt == qt) {  // diagonal tile: causal mask
#pragma unroll
      for (int f = 0; f < 4; ++f) {
        int keyl = f * 16 + (lane & 15);
#pragma unroll
        for (int i = 0; i < 4; ++i) {
          int ql = wave * 16 + (lane >> 4) * 4 + i;
          if (keyl > ql) sacc[f][i] = -__builtin_inff();
        }
      }
    }
    // online softmax (row reduce across the 16-lane column group)
    float pv[4][4];
#pragma unroll
    for (int i = 0; i < 4; ++i) {
      float mx = fmaxf(fmaxf(sacc[0][i], sacc[1][i]), fmaxf(sacc[2][i], sacc[3][i]));
      mx = fmaxf(mx, __shfl_xor(mx, 1));
      mx = fmaxf(mx, __shfl_xor(mx, 2));
      mx = fmaxf(mx, __shfl_xor(mx, 4));
      mx = fmaxf(mx, __shfl_xor(mx, 8));
      float mN = fmaxf(m_i[i], mx);
      float sc = __expf(m_i[i] - mN);
      m_i[i] = mN;
#pragma unroll
      for (int f = 0; f < 4; ++f) pv[f][i] = __expf(sacc[f][i] - mN);
      float sm = pv[0][i] + pv[1][i] + pv[2][i] + pv[3][i];
      sm += __shfl_xor(sm, 1);
      sm += __shfl_xor(sm, 2);
      sm += __shfl_xor(sm, 4);
      sm += __shfl_xor(sm, 8);
      l_i[i] = l_i[i] * sc + sm;
#pragma unroll
      for (int f2 = 0; f2 < 4; ++f2) O[f2][i] *= sc;
    }
    // P -> per-wave LDS (swizzled), then PV
#pragma unroll
    for (int f = 0; f < 4; ++f) {
      int col = f * 16 + (lane & 15);
#pragma unroll
      for (int i = 0; i < 4; ++i) {
        int r = (lane >> 4) * 4 + i;
        *(uint16_t*)((char*)Pw + ((r * 128 + col * 2) ^ ((r & 7) << 4))) = f2bf(pv[f][i]);
      }
    }
#pragma unroll
    for (int kx = 0; kx < 2; ++kx) {
      int rp = lane & 15;
      bf8_t ap = *(const bf8_t*)((const char*)Pw +
                  ((rp * 128 + (lane >> 4) * 16 + kx * 64) ^ ((rp & 7) << 4)));
#pragma unroll
      for (int f2 = 0; f2 < 4; ++f2) {
        int rv = f2 * 16 + (lane & 15);
        bf8_t bv = *(const bf8_t*)((const char*)Vs + rv * 128 +
                    ((((lane >> 4) + kx * 4) ^ (rv & 7)) * 16));
        O[f2] = __builtin_amdgcn_mfma_f32_16x16x32_bf16(ap, bv, O[f2], 0, 0, 0);
      }
    }
  }
  // epilogue: O / l, write Y as [B,S,H*HD] bf16
#pragma unroll
  for (int f2 = 0; f2 < 4; ++f2)
#pragma unroll
    for (int i = 0; i < 4; ++i) {
      int q = qrow0 + (lane >> 4) * 4 + i;
      int d = f2 * 16 + (lane & 15);
      Yb[((size_t)b * SEQ + q) * D_MODEL + h * HD + d] = f2bf(O[f2][i] / l_i[i]);
    }
}

extern "C" void kernel_launch(void* const* d_in, const int* in_sizes, int n_in,
                              void* d_out, int out_size, void* d_ws, size_t ws_size,
                              hipStream_t stream) {
  const float* x     = (const float*)d_in[0];
  const float* wqkv  = (const float*)d_in[1];
  const float* bqkv  = (const float*)d_in[2];
  const float* wproj = (const float*)d_in[3];
  const float* bproj = (const float*)d_in[4];
  float* out = (float*)d_out;
  char* ws = (char*)d_ws;
  // workspace layout (total 92,274,688 B)
  uint16_t* xb     = (uint16_t*)(ws);                          // 16 MiB
  uint16_t* wqkvT  = (uint16_t*)(ws + 16777216);               // 6 MiB
  uint16_t* wprojT = (uint16_t*)(ws + 16777216 + 6291456);     // 2 MiB
  uint16_t* Qb     = (uint16_t*)(ws + 25165824);               // 16 MiB [B,H,S,64]
  uint16_t* Kb     = (uint16_t*)(ws + 25165824 + 16777216);    // 16 MiB [B,H,S,64]
  uint16_t* VTb    = (uint16_t*)(ws + 25165824 + 2 * 16777216);// 16 MiB [B,H,64,S]
  uint16_t* Yb     = (uint16_t*)(ws + 25165824 + 3 * 16777216);// 16 MiB [B,S,H*64]

  k_cvt<<<dim3(MROWS * D_MODEL / 4 / 256), dim3(256), 0, stream>>>(x, xb, MROWS * D_MODEL / 4);
  k_tcvt<<<dim3(3 * D_MODEL / 32, D_MODEL / 32), dim3(256), 0, stream>>>(wqkv, wqkvT, D_MODEL, 3 * D_MODEL);
  k_tcvt<<<dim3(D_MODEL / 32, D_MODEL / 32), dim3(256), 0, stream>>>(wproj, wprojT, D_MODEL, D_MODEL);
  k_gemm_qkv<<<dim3(3 * D_MODEL / 128, MROWS / 128), dim3(256), 0, stream>>>(xb, wqkvT, bqkv, Qb, Kb, VTb);
  k_attn<<<dim3(SEQ / 64, NB * NH), dim3(256), 0, stream>>>(Qb, Kb, VTb, Yb);
  k_gemm_proj<<<dim3(D_MODEL / 128, MROWS / 128), dim3(256), 0, stream>>>(Yb, wprojT, bproj, out);
}

// Round 2
// 339.814 us; speedup vs baseline: 1.2653x; 1.2653x over previous
//
#include <hip/hip_runtime.h>
#include <stdint.h>

typedef __attribute__((ext_vector_type(8))) short bf8_t;
typedef __attribute__((ext_vector_type(4))) float f4_t;

#define D_MODEL 1024
#define SEQ 2048
#define NB 4
#define NH 16
#define HD 64
#define MROWS (NB * SEQ)

__device__ __forceinline__ uint16_t f2bf(float f) {
  uint32_t u = __builtin_bit_cast(uint32_t, f);
  u += 0x7FFFu + ((u >> 16) & 1u);
  return (uint16_t)(u >> 16);
}

__device__ __forceinline__ void gload16(const void* g, void* l) {
  __builtin_amdgcn_global_load_lds(
      (const __attribute__((address_space(1))) void*)g,
      (__attribute__((address_space(3))) void*)l, 16, 0, 0);
}

// ---- fp32 -> bf16 elementwise (vectorized) ----
__global__ void k_cvt(const float* __restrict__ in, uint16_t* __restrict__ out, int n4) {
  int i = blockIdx.x * blockDim.x + threadIdx.x;
  if (i >= n4) return;
  float4 v = ((const float4*)in)[i];
  ushort4 o;
  o.x = f2bf(v.x); o.y = f2bf(v.y); o.z = f2bf(v.z); o.w = f2bf(v.w);
  ((ushort4*)out)[i] = o;
}

// ---- transpose+convert: in [K][N] fp32 -> out [N][K] bf16 ----
__global__ void k_tcvt(const float* __restrict__ in, uint16_t* __restrict__ out, int K, int N) {
  __shared__ float tile[32][33];
  int nb = blockIdx.x * 32, kb = blockIdx.y * 32;
  int tx = threadIdx.x & 31, ty = threadIdx.x >> 5;
#pragma unroll
  for (int i = 0; i < 4; ++i)
    tile[ty + i * 8][tx] = in[(size_t)(kb + ty + i * 8) * N + nb + tx];
  __syncthreads();
#pragma unroll
  for (int i = 0; i < 4; ++i)
    out[(size_t)(nb + ty + i * 8) * K + kb + tx] = f2bf(tile[tx][ty + i * 8]);
}

// ---- shared GEMM mainloop: C[128x128] = A[128xK] * Bt[128xK]^T, K=1024, BK=64 ----
__device__ __forceinline__ void gemm_mainloop(const uint16_t* __restrict__ A,
                                              const uint16_t* __restrict__ Bt,
                                              int mBase, int nBase, f4_t acc[4][4],
                                              uint16_t* As, uint16_t* Bs) {
  const int t = threadIdx.x;
  const int lane = t & 63;
  const int wm = (t >> 6) >> 1, wn = (t >> 6) & 1;
  for (int ks = 0; ks < D_MODEL / 64; ++ks) {
#pragma unroll
    for (int iss = 0; iss < 4; ++iss) {
      int p = iss * 256 + t;
      int r = p >> 3;
      int c = (p & 7) ^ (r & 7);
      gload16(A + (size_t)(mBase + r) * D_MODEL + ks * 64 + c * 8, As + p * 8);
      gload16(Bt + (size_t)(nBase + r) * D_MODEL + ks * 64 + c * 8, Bs + p * 8);
    }
    __syncthreads();
    bf8_t af[4][2], bfr[4][2];
#pragma unroll
    for (int mi = 0; mi < 4; ++mi) {
      int r = wm * 64 + mi * 16 + (lane & 15);
#pragma unroll
      for (int kx = 0; kx < 2; ++kx) {
        int gl = (lane >> 4) + kx * 4;
        af[mi][kx] = *(const bf8_t*)((const char*)As + r * 128 + ((gl ^ (r & 7)) * 16));
      }
    }
#pragma unroll
    for (int ni = 0; ni < 4; ++ni) {
      int r = wn * 64 + ni * 16 + (lane & 15);
#pragma unroll
      for (int kx = 0; kx < 2; ++kx) {
        int gl = (lane >> 4) + kx * 4;
        bfr[ni][kx] = *(const bf8_t*)((const char*)Bs + r * 128 + ((gl ^ (r & 7)) * 16));
      }
    }
#pragma unroll
    for (int mi = 0; mi < 4; ++mi)
#pragma unroll
      for (int ni = 0; ni < 4; ++ni) {
        acc[mi][ni] = __builtin_amdgcn_mfma_f32_16x16x32_bf16(af[mi][0], bfr[ni][0], acc[mi][ni], 0, 0, 0);
        acc[mi][ni] = __builtin_amdgcn_mfma_f32_16x16x32_bf16(af[mi][1], bfr[ni][1], acc[mi][ni], 0, 0, 0);
      }
    __syncthreads();
  }
}

// ---- QKV GEMM: epilogue routes to Q (scaled 1/8), K, and transposed V ----
__global__ __launch_bounds__(256, 2) void k_gemm_qkv(
    const uint16_t* __restrict__ A, const uint16_t* __restrict__ Bt,
    const float* __restrict__ bias,
    uint16_t* __restrict__ Qb, uint16_t* __restrict__ Kb, uint16_t* __restrict__ VTb) {
  __shared__ uint16_t As[128 * 64];
  __shared__ uint16_t Bs[128 * 64];
  f4_t acc[4][4] = {};
  int mBase = blockIdx.y * 128, nBase = blockIdx.x * 128;
  gemm_mainloop(A, Bt, mBase, nBase, acc, As, Bs);
  const int lane = threadIdx.x & 63;
  const int wm = (threadIdx.x >> 6) >> 1, wn = (threadIdx.x >> 6) & 1;
#pragma unroll
  for (int mi = 0; mi < 4; ++mi)
#pragma unroll
    for (int ni = 0; ni < 4; ++ni)
#pragma unroll
      for (int i = 0; i < 4; ++i) {
        int m = mBase + wm * 64 + mi * 16 + (lane >> 4) * 4 + i;
        int n = nBase + wn * 64 + ni * 16 + (lane & 15);
        float v = acc[mi][ni][i] + bias[n];
        int b = m >> 11, s = m & 2047;
        int which = n >> 10, hn = n & 1023;
        int h = hn >> 6, d = hn & 63;
        size_t bh = (size_t)(b * NH + h);
        if (which == 0)      Qb[(bh * SEQ + s) * HD + d] = f2bf(v * 0.125f);
        else if (which == 1) Kb[(bh * SEQ + s) * HD + d] = f2bf(v);
        else                 VTb[(bh * HD + d) * SEQ + s] = f2bf(v);
      }
}

// ---- proj GEMM: fp32 output + bias ----
__global__ __launch_bounds__(256, 2) void k_gemm_proj(
    const uint16_t* __restrict__ A, const uint16_t* __restrict__ Bt,
    const float* __restrict__ bias, float* __restrict__ out) {
  __shared__ uint16_t As[128 * 64];
  __shared__ uint16_t Bs[128 * 64];
  f4_t acc[4][4] = {};
  int mBase = blockIdx.y * 128, nBase = blockIdx.x * 128;
  gemm_mainloop(A, Bt, mBase, nBase, acc, As, Bs);
  const int lane = threadIdx.x & 63;
  const int wm = (threadIdx.x >> 6) >> 1, wn = (threadIdx.x >> 6) & 1;
#pragma unroll
  for (int mi = 0; mi < 4; ++mi)
#pragma unroll
    for (int ni = 0; ni < 4; ++ni)
#pragma unroll
      for (int i = 0; i < 4; ++i) {
        int m = mBase + wm * 64 + mi * 16 + (lane >> 4) * 4 + i;
        int n = nBase + wn * 64 + ni * 16 + (lane & 15);
        out[(size_t)m * D_MODEL + n] = acc[mi][ni][i] + bias[n];
      }
}

// ---- flash attention, causal.
// Block: 512 threads (8 waves), QBLK=128 (16 q-rows/wave), KVBLK=64 double-buffered.
// grid (bh fast, qt slow): bh%8 pins each head's K/V to one XCD's L2.
// Raw s_barrier + counted vmcnt(2): next tile's global_load_lds stays in
// flight across the compute of the current tile (T3/T4 minimum pattern).
__global__ __launch_bounds__(512, 4) void k_attn(
    const uint16_t* __restrict__ Qb, const uint16_t* __restrict__ Kb,
    const uint16_t* __restrict__ VTb, uint16_t* __restrict__ Yb) {
  __shared__ uint16_t Ks[2][64 * 64];
  __shared__ uint16_t Vs[2][64 * 64];
  __shared__ uint16_t Ps[8][16 * 64];
  const int t = threadIdx.x, lane = t & 63, wave = t >> 6;
  const int bh = blockIdx.x, qt = blockIdx.y;
  const int b = bh >> 4, h = bh & 15;
  const int qrow0 = qt * 128 + wave * 16;
  // Q fragments hoisted to registers (Q pre-scaled by 1/8 at QKV epilogue)
  const uint16_t* Qrow = Qb + ((size_t)bh * SEQ + qrow0 + (lane & 15)) * HD;
  bf8_t aq[2];
  aq[0] = *(const bf8_t*)(Qrow + (lane >> 4) * 8);
  aq[1] = *(const bf8_t*)(Qrow + (lane >> 4) * 8 + 32);
  float m_i[4], l_i[4];
  f4_t O[4] = {};
#pragma unroll
  for (int i = 0; i < 4; ++i) { m_i[i] = -__builtin_inff(); l_i[i] = 0.f; }
  uint16_t* Pw = Ps[wave];

  const int sr = t >> 3;                  // staging row 0..63
  const int sc = (t & 7) ^ (sr & 7);      // pre-swizzled source granule
  const uint16_t* Kg = Kb + ((size_t)bh * SEQ + sr) * HD + sc * 8;
  const uint16_t* Vg = VTb + ((size_t)bh * HD + sr) * SEQ + sc * 8;

  const int nt = 2 * qt + 2;  // KV tiles covering keys [0, (qt+1)*128)
  // prologue: stage tile 0 into buf 0
  gload16(Kg + 0, Ks[0] + t * 8);
  gload16(Vg + 0, Vs[0] + t * 8);

  for (int kt = 0; kt < nt; ++kt) {
    const int cur = kt & 1;
    if (kt + 1 < nt) {
      gload16(Kg + (size_t)(kt + 1) * 64 * HD, Ks[cur ^ 1] + t * 8);
      gload16(Vg + (kt + 1) * 64, Vs[cur ^ 1] + t * 8);
      asm volatile("s_waitcnt vmcnt(2)" ::: "memory");  // tile kt landed; kt+1 in flight
    } else {
      asm volatile("s_waitcnt vmcnt(0)" ::: "memory");
    }
    __builtin_amdgcn_s_barrier();

    const uint16_t* Kt = Ks[cur];
    const uint16_t* Vt = Vs[cur];
    // S = Q K^T  (16 q-rows x 64 keys, 4 col-fragments)
    f4_t sacc[4] = {};
#pragma unroll
    for (int f = 0; f < 4; ++f) {
      int kr = f * 16 + (lane & 15);
#pragma unroll
      for (int kx = 0; kx < 2; ++kx) {
        int gl = (lane >> 4) + kx * 4;
        bf8_t bk = *(const bf8_t*)((const char*)Kt + kr * 128 + ((gl ^ (kr & 7)) * 16));
        sacc[f] = __builtin_amdgcn_mfma_f32_16x16x32_bf16(aq[kx], bk, sacc[f], 0, 0, 0);
      }
    }
    if (kt >= 2 * qt) {  // diagonal-intersecting tile: causal mask (global idx)
#pragma unroll
      for (int f = 0; f < 4; ++f) {
        int key = kt * 64 + f * 16 + (lane & 15);
#pragma unroll
        for (int i = 0; i < 4; ++i) {
          int row = qrow0 + (lane >> 4) * 4 + i;
          if (key > row) sacc[f][i] = -__builtin_inff();
        }
      }
    }
    // online softmax (row reduce across the 16-lane column group)
    float pv[4][4];
#pragma unroll
    for (int i = 0; i < 4; ++i) {
      float mx = fmaxf(fmaxf(sacc[0][i], sacc[1][i]), fmaxf(sacc[2][i], sacc[3][i]));
      mx = fmaxf(mx, __shfl_xor(mx, 1));
      mx = fmaxf(mx, __shfl_xor(mx, 2));
      mx = fmaxf(mx, __shfl_xor(mx, 4));
      mx = fmaxf(mx, __shfl_xor(mx, 8));
      float mN = fmaxf(m_i[i], mx);
      float sc2 = __expf(m_i[i] - mN);
      m_i[i] = mN;
#pragma unroll
      for (int f = 0; f < 4; ++f) pv[f][i] = __expf(sacc[f][i] - mN);
      float sm = pv[0][i] + pv[1][i] + pv[2][i] + pv[3][i];
      sm += __shfl_xor(sm, 1);
      sm += __shfl_xor(sm, 2);
      sm += __shfl_xor(sm, 4);
      sm += __shfl_xor(sm, 8);
      l_i[i] = l_i[i] * sc2 + sm;
#pragma unroll
      for (int f2 = 0; f2 < 4; ++f2) O[f2][i] *= sc2;
    }
    // P -> per-wave LDS (swizzled), then PV
#pragma unroll
    for (int f = 0; f < 4; ++f) {
      int col = f * 16 + (lane & 15);
#pragma unroll
      for (int i = 0; i < 4; ++i) {
        int r = (lane >> 4) * 4 + i;
        *(uint16_t*)((char*)Pw + ((r * 128 + col * 2) ^ ((r & 7) << 4))) = f2bf(pv[f][i]);
      }
    }
#pragma unroll
    for (int kx = 0; kx < 2; ++kx) {
      int rp = lane & 15;
      bf8_t ap = *(const bf8_t*)((const char*)Pw +
                  ((rp * 128 + (lane >> 4) * 16 + kx * 64) ^ ((rp & 7) << 4)));
#pragma unroll
      for (int f2 = 0; f2 < 4; ++f2) {
        int rv = f2 * 16 + (lane & 15);
        bf8_t bv = *(const bf8_t*)((const char*)Vt + rv * 128 +
                    ((((lane >> 4) + kx * 4) ^ (rv & 7)) * 16));
        O[f2] = __builtin_amdgcn_mfma_f32_16x16x32_bf16(ap, bv, O[f2], 0, 0, 0);
      }
    }
    asm volatile("s_waitcnt lgkmcnt(0)" ::: "memory");  // all LDS reads of buf[cur] done
    __builtin_amdgcn_s_barrier();                       // before next stage overwrites
  }
  // epilogue: O / l, write Y as [B,S,H*HD] bf16
#pragma unroll
  for (int f2 = 0; f2 < 4; ++f2)
#pragma unroll
    for (int i = 0; i < 4; ++i) {
      int q = qrow0 + (lane >> 4) * 4 + i;
      int d = f2 * 16 + (lane & 15);
      Yb[((size_t)b * SEQ + q) * D_MODEL + h * HD + d] = f2bf(O[f2][i] / l_i[i]);
    }
}

extern "C" void kernel_launch(void* const* d_in, const int* in_sizes, int n_in,
                              void* d_out, int out_size, void* d_ws, size_t ws_size,
                              hipStream_t stream) {
  const float* x     = (const float*)d_in[0];
  const float* wqkv  = (const float*)d_in[1];
  const float* bqkv  = (const float*)d_in[2];
  const float* wproj = (const float*)d_in[3];
  const float* bproj = (const float*)d_in[4];
  float* out = (float*)d_out;
  char* ws = (char*)d_ws;
  uint16_t* xb     = (uint16_t*)(ws);                          // 16 MiB
  uint16_t* wqkvT  = (uint16_t*)(ws + 16777216);               // 6 MiB
  uint16_t* wprojT = (uint16_t*)(ws + 16777216 + 6291456);     // 2 MiB
  uint16_t* Qb     = (uint16_t*)(ws + 25165824);               // 16 MiB [B,H,S,64]
  uint16_t* Kb     = (uint16_t*)(ws + 25165824 + 16777216);    // 16 MiB [B,H,S,64]
  uint16_t* VTb    = (uint16_t*)(ws + 25165824 + 2 * 16777216);// 16 MiB [B,H,64,S]
  uint16_t* Yb     = (uint16_t*)(ws + 25165824 + 3 * 16777216);// 16 MiB [B,S,H*64]

  k_cvt<<<dim3(MROWS * D_MODEL / 4 / 256), dim3(256), 0, stream>>>(x, xb, MROWS * D_MODEL / 4);
  k_tcvt<<<dim3(3 * D_MODEL / 32, D_MODEL / 32), dim3(256), 0, stream>>>(wqkv, wqkvT, D_MODEL, 3 * D_MODEL);
  k_tcvt<<<dim3(D_MODEL / 32, D_MODEL / 32), dim3(256), 0, stream>>>(wproj, wprojT, D_MODEL, D_MODEL);
  k_gemm_qkv<<<dim3(3 * D_MODEL / 128, MROWS / 128), dim3(256), 0, stream>>>(xb, wqkvT, bqkv, Qb, Kb, VTb);
  // bh fastest -> bh%8 keeps each head's K/V resident in one XCD's L2
  k_attn<<<dim3(NB * NH, SEQ / 128), dim3(512), 0, stream>>>(Qb, Kb, VTb, Yb);
  k_gemm_proj<<<dim3(D_MODEL / 128, MROWS / 128), dim3(256), 0, stream>>>(Yb, wprojT, bproj, out);
}

// Round 3
// 280.126 us; speedup vs baseline: 1.5349x; 1.2131x over previous
//
#include <hip/hip_runtime.h>
#include <stdint.h>

typedef __attribute__((ext_vector_type(8))) short bf8_t;
typedef __attribute__((ext_vector_type(4))) short bf4_t;
typedef __attribute__((ext_vector_type(4))) float f4_t;

#define D_MODEL 1024
#define SEQ 2048
#define NB 4
#define NH 16
#define HD 64
#define MROWS (NB * SEQ)
// Q pre-scale folds 1/sqrt(64) and log2(e): scores land in exp2 domain
#define QSCALE 0.1803368801111204f

__device__ __forceinline__ uint16_t f2bf(float f) {
  uint32_t u = __builtin_bit_cast(uint32_t, f);
  u += 0x7FFFu + ((u >> 16) & 1u);
  return (uint16_t)(u >> 16);
}

__device__ __forceinline__ void gload16(const void* g, void* l) {
  __builtin_amdgcn_global_load_lds(
      (const __attribute__((address_space(1))) void*)g,
      (__attribute__((address_space(3))) void*)l, 16, 0, 0);
}

// ---- fp32 -> bf16 elementwise (vectorized) ----
__global__ void k_cvt(const float* __restrict__ in, uint16_t* __restrict__ out, int n4) {
  int i = blockIdx.x * blockDim.x + threadIdx.x;
  if (i >= n4) return;
  float4 v = ((const float4*)in)[i];
  ushort4 o;
  o.x = f2bf(v.x); o.y = f2bf(v.y); o.z = f2bf(v.z); o.w = f2bf(v.w);
  ((ushort4*)out)[i] = o;
}

// ---- transpose+convert: in [K][N] fp32 -> out [N][K] bf16 ----
__global__ void k_tcvt(const float* __restrict__ in, uint16_t* __restrict__ out, int K, int N) {
  __shared__ float tile[32][33];
  int nb = blockIdx.x * 32, kb = blockIdx.y * 32;
  int tx = threadIdx.x & 31, ty = threadIdx.x >> 5;
#pragma unroll
  for (int i = 0; i < 4; ++i)
    tile[ty + i * 8][tx] = in[(size_t)(kb + ty + i * 8) * N + nb + tx];
  __syncthreads();
#pragma unroll
  for (int i = 0; i < 4; ++i)
    out[(size_t)(nb + ty + i * 8) * K + kb + tx] = f2bf(tile[tx][ty + i * 8]);
}

// ---- shared GEMM mainloop: C[128x128] = A[128xK] * Bt[128xK]^T, K=1024, BK=64 ----
__device__ __forceinline__ void gemm_mainloop(const uint16_t* __restrict__ A,
                                              const uint16_t* __restrict__ Bt,
                                              int mBase, int nBase, f4_t acc[4][4],
                                              uint16_t* As, uint16_t* Bs) {
  const int t = threadIdx.x;
  const int lane = t & 63;
  const int wm = (t >> 6) >> 1, wn = (t >> 6) & 1;
  for (int ks = 0; ks < D_MODEL / 64; ++ks) {
#pragma unroll
    for (int iss = 0; iss < 4; ++iss) {
      int p = iss * 256 + t;
      int r = p >> 3;
      int c = (p & 7) ^ (r & 7);
      gload16(A + (size_t)(mBase + r) * D_MODEL + ks * 64 + c * 8, As + p * 8);
      gload16(Bt + (size_t)(nBase + r) * D_MODEL + ks * 64 + c * 8, Bs + p * 8);
    }
    __syncthreads();
    bf8_t af[4][2], bfr[4][2];
#pragma unroll
    for (int mi = 0; mi < 4; ++mi) {
      int r = wm * 64 + mi * 16 + (lane & 15);
#pragma unroll
      for (int kx = 0; kx < 2; ++kx) {
        int gl = (lane >> 4) + kx * 4;
        af[mi][kx] = *(const bf8_t*)((const char*)As + r * 128 + ((gl ^ (r & 7)) * 16));
      }
    }
#pragma unroll
    for (int ni = 0; ni < 4; ++ni) {
      int r = wn * 64 + ni * 16 + (lane & 15);
#pragma unroll
      for (int kx = 0; kx < 2; ++kx) {
        int gl = (lane >> 4) + kx * 4;
        bfr[ni][kx] = *(const bf8_t*)((const char*)Bs + r * 128 + ((gl ^ (r & 7)) * 16));
      }
    }
#pragma unroll
    for (int mi = 0; mi < 4; ++mi)
#pragma unroll
      for (int ni = 0; ni < 4; ++ni) {
        acc[mi][ni] = __builtin_amdgcn_mfma_f32_16x16x32_bf16(af[mi][0], bfr[ni][0], acc[mi][ni], 0, 0, 0);
        acc[mi][ni] = __builtin_amdgcn_mfma_f32_16x16x32_bf16(af[mi][1], bfr[ni][1], acc[mi][ni], 0, 0, 0);
      }
    __syncthreads();
  }
}

// ---- QKV GEMM: epilogue routes to Q (scaled QSCALE), K, and transposed V ----
__global__ __launch_bounds__(256, 2) void k_gemm_qkv(
    const uint16_t* __restrict__ A, const uint16_t* __restrict__ Bt,
    const float* __restrict__ bias,
    uint16_t* __restrict__ Qb, uint16_t* __restrict__ Kb, uint16_t* __restrict__ VTb) {
  __shared__ uint16_t As[128 * 64];
  __shared__ uint16_t Bs[128 * 64];
  f4_t acc[4][4] = {};
  int mBase = blockIdx.y * 128, nBase = blockIdx.x * 128;
  gemm_mainloop(A, Bt, mBase, nBase, acc, As, Bs);
  const int lane = threadIdx.x & 63;
  const int wm = (threadIdx.x >> 6) >> 1, wn = (threadIdx.x >> 6) & 1;
#pragma unroll
  for (int mi = 0; mi < 4; ++mi)
#pragma unroll
    for (int ni = 0; ni < 4; ++ni)
#pragma unroll
      for (int i = 0; i < 4; ++i) {
        int m = mBase + wm * 64 + mi * 16 + (lane >> 4) * 4 + i;
        int n = nBase + wn * 64 + ni * 16 + (lane & 15);
        float v = acc[mi][ni][i] + bias[n];
        int b = m >> 11, s = m & 2047;
        int which = n >> 10, hn = n & 1023;
        int h = hn >> 6, d = hn & 63;
        size_t bh = (size_t)(b * NH + h);
        if (which == 0)      Qb[(bh * SEQ + s) * HD + d] = f2bf(v * QSCALE);
        else if (which == 1) Kb[(bh * SEQ + s) * HD + d] = f2bf(v);
        else                 VTb[(bh * HD + d) * SEQ + s] = f2bf(v);
      }
}

// ---- proj GEMM: fp32 output + bias ----
__global__ __launch_bounds__(256, 2) void k_gemm_proj(
    const uint16_t* __restrict__ A, const uint16_t* __restrict__ Bt,
    const float* __restrict__ bias, float* __restrict__ out) {
  __shared__ uint16_t As[128 * 64];
  __shared__ uint16_t Bs[128 * 64];
  f4_t acc[4][4] = {};
  int mBase = blockIdx.y * 128, nBase = blockIdx.x * 128;
  gemm_mainloop(A, Bt, mBase, nBase, acc, As, Bs);
  const int lane = threadIdx.x & 63;
  const int wm = (threadIdx.x >> 6) >> 1, wn = (threadIdx.x >> 6) & 1;
#pragma unroll
  for (int mi = 0; mi < 4; ++mi)
#pragma unroll
    for (int ni = 0; ni < 4; ++ni)
#pragma unroll
      for (int i = 0; i < 4; ++i) {
        int m = mBase + wm * 64 + mi * 16 + (lane >> 4) * 4 + i;
        int n = nBase + wn * 64 + ni * 16 + (lane & 15);
        out[(size_t)m * D_MODEL + n] = acc[mi][ni][i] + bias[n];
      }
}

// ---- flash attention, causal. Swapped-QK^T (S^T = K·Q^T) => P stays in
// registers (no P LDS), per-lane row stats (2 shuffles per reduce).
// Block handles TWO q-tiles (qt = pr and 15-pr) => every block = 34 KV tiles
// (perfect load balance). bh fast grid axis pins K/V to one XCD L2.
__global__ __launch_bounds__(512, 4) void k_attn(
    const uint16_t* __restrict__ Qb, const uint16_t* __restrict__ Kb,
    const uint16_t* __restrict__ VTb, uint16_t* __restrict__ Yb) {
  __shared__ uint16_t Ks[2][64 * 64];
  __shared__ uint16_t Vs[2][64 * 64];
  const int t = threadIdx.x, lane = t & 63, wave = t >> 6;
  const int g = lane >> 4, a = lane & 15;
  const int bh = blockIdx.x, pr = blockIdx.y;
  const int b = bh >> 4, h = bh & 15;

  const int sr = t >> 3;                  // staging row 0..63
  const int scol = (t & 7) ^ (sr & 7);    // pre-swizzled source granule
  const uint16_t* Kg = Kb + ((size_t)bh * SEQ + sr) * HD + scol * 8;
  const uint16_t* Vg = VTb + ((size_t)bh * HD + sr) * SEQ + scol * 8;

#pragma unroll 1
  for (int seg = 0; seg < 2; ++seg) {
    const int qt = seg ? (15 - pr) : pr;
    const int qrow0 = qt * 128 + wave * 16;
    // Q fragments (pre-scaled by QSCALE at QKV epilogue); q-row = lane&15
    const uint16_t* Qrow = Qb + ((size_t)bh * SEQ + qrow0 + a) * HD;
    bf8_t aq[2];
    aq[0] = *(const bf8_t*)(Qrow + g * 8);
    aq[1] = *(const bf8_t*)(Qrow + g * 8 + 32);
    float m_i = -__builtin_inff(), l_i = 0.f;
    f4_t O[4] = {};

    const int nt = 2 * qt + 2;
    gload16(Kg, Ks[0] + t * 8);   // prologue: tile 0 -> buf 0
    gload16(Vg, Vs[0] + t * 8);

    for (int kt = 0; kt < nt; ++kt) {
      const int cur = kt & 1;
      if (kt + 1 < nt) {
        gload16(Kg + (size_t)(kt + 1) * 64 * HD, Ks[cur ^ 1] + t * 8);
        gload16(Vg + (kt + 1) * 64, Vs[cur ^ 1] + t * 8);
        asm volatile("s_waitcnt vmcnt(2)" ::: "memory");
      } else {
        asm volatile("s_waitcnt vmcnt(0)" ::: "memory");
      }
      __builtin_amdgcn_s_barrier();

      const uint16_t* Kt = Ks[cur];
      const uint16_t* Vt = Vs[cur];
      // skip tiles fully above the causal diagonal for this wave
      if (kt * 64 <= qrow0 + 15) {
        // S^T = K·Q^T: sacc[f][i] = S[key][q], key = kt*64+f*16+g*4+i, q = qrow0+a
        f4_t sacc[4] = {};
#pragma unroll
        for (int f = 0; f < 4; ++f) {
          int kr = f * 16 + a;
#pragma unroll
          for (int kx = 0; kx < 2; ++kx) {
            int gl = g + kx * 4;
            bf8_t bk = *(const bf8_t*)((const char*)Kt + kr * 128 + ((gl ^ (kr & 7)) * 16));
            sacc[f] = __builtin_amdgcn_mfma_f32_16x16x32_bf16(bk, aq[kx], sacc[f], 0, 0, 0);
          }
        }
        if (kt >= 2 * qt) {  // diagonal-intersecting tile: causal mask
          int q = qrow0 + a;
#pragma unroll
          for (int f = 0; f < 4; ++f)
#pragma unroll
            for (int i = 0; i < 4; ++i) {
              int key = kt * 64 + f * 16 + g * 4 + i;
              if (key > q) sacc[f][i] = -__builtin_inff();
            }
        }
        // per-lane row max over 16 values + 2 cross-group shuffles
        float mx = sacc[0][0];
#pragma unroll
        for (int f = 0; f < 4; ++f)
#pragma unroll
          for (int i = 0; i < 4; ++i) mx = fmaxf(mx, sacc[f][i]);
        mx = fmaxf(mx, __shfl_xor(mx, 16));
        mx = fmaxf(mx, __shfl_xor(mx, 32));
        // defer-max (T13): only rescale when max grew by > 8 (exp2 domain)
        if (__any(mx > m_i + 8.0f)) {
          float mN = fmaxf(m_i, mx);
          float sc2 = exp2f(m_i - mN);
          m_i = mN;
          l_i *= sc2;
#pragma unroll
          for (int i = 0; i < 4; ++i) {
            float s4 = __shfl(sc2, (lane & 48) | (g * 4 + i));
#pragma unroll
            for (int f2 = 0; f2 < 4; ++f2) O[f2][i] *= s4;
          }
        }
        float pvv[4][4];
        float sm = 0.f;
#pragma unroll
        for (int f = 0; f < 4; ++f)
#pragma unroll
          for (int i = 0; i < 4; ++i) {
            pvv[f][i] = exp2f(sacc[f][i] - m_i);
            sm += pvv[f][i];
          }
        sm += __shfl_xor(sm, 16);
        sm += __shfl_xor(sm, 32);
        l_i += sm;
        // pack P into PV A-frags in-register (k-order kappa(g,j)=32kx+16(j>>2)+4g+(j&3))
        bf8_t pa[2];
#pragma unroll
        for (int kx = 0; kx < 2; ++kx)
#pragma unroll
          for (int j = 0; j < 8; ++j)
            pa[kx][j] = (short)f2bf(pvv[2 * kx + (j >> 2)][j & 3]);
        // PV: B-frag built with the SAME kappa ordering from V^T rows
#pragma unroll
        for (int kx = 0; kx < 2; ++kx)
#pragma unroll
          for (int f2 = 0; f2 < 4; ++f2) {
            int rv = f2 * 16 + a;
            int sw = (rv & 7) << 4;
            bf4_t lo = *(const bf4_t*)((const char*)Vt + rv * 128 + ((64 * kx + 8 * g) ^ sw));
            bf4_t hi = *(const bf4_t*)((const char*)Vt + rv * 128 + ((64 * kx + 32 + 8 * g) ^ sw));
            bf8_t bv = __builtin_shufflevector(lo, hi, 0, 1, 2, 3, 4, 5, 6, 7);
            O[f2] = __builtin_amdgcn_mfma_f32_16x16x32_bf16(pa[kx], bv, O[f2], 0, 0, 0);
          }
      }
      asm volatile("s_waitcnt lgkmcnt(0)" ::: "memory");
      __builtin_amdgcn_s_barrier();
    }
    // epilogue: O rows q = qrow0+g*4+i need l of that row (shuffle from P-layout)
    float rinv[4];
#pragma unroll
    for (int i = 0; i < 4; ++i)
      rinv[i] = 1.0f / __shfl(l_i, (lane & 48) | (g * 4 + i));
#pragma unroll
    for (int f2 = 0; f2 < 4; ++f2)
#pragma unroll
      for (int i = 0; i < 4; ++i) {
        int q = qrow0 + g * 4 + i;
        int d = f2 * 16 + a;
        Yb[((size_t)b * SEQ + q) * D_MODEL + h * HD + d] = f2bf(O[f2][i] * rinv[i]);
      }
  }
}

extern "C" void kernel_launch(void* const* d_in, const int* in_sizes, int n_in,
                              void* d_out, int out_size, void* d_ws, size_t ws_size,
                              hipStream_t stream) {
  const float* x     = (const float*)d_in[0];
  const float* wqkv  = (const float*)d_in[1];
  const float* bqkv  = (const float*)d_in[2];
  const float* wproj = (const float*)d_in[3];
  const float* bproj = (const float*)d_in[4];
  float* out = (float*)d_out;
  char* ws = (char*)d_ws;
  uint16_t* xb     = (uint16_t*)(ws);                          // 16 MiB
  uint16_t* wqkvT  = (uint16_t*)(ws + 16777216);               // 6 MiB
  uint16_t* wprojT = (uint16_t*)(ws + 16777216 + 6291456);     // 2 MiB
  uint16_t* Qb     = (uint16_t*)(ws + 25165824);               // 16 MiB [B,H,S,64]
  uint16_t* Kb     = (uint16_t*)(ws + 25165824 + 16777216);    // 16 MiB [B,H,S,64]
  uint16_t* VTb    = (uint16_t*)(ws + 25165824 + 2 * 16777216);// 16 MiB [B,H,64,S]
  uint16_t* Yb     = (uint16_t*)(ws + 25165824 + 3 * 16777216);// 16 MiB [B,S,H*64]

  k_cvt<<<dim3(MROWS * D_MODEL / 4 / 256), dim3(256), 0, stream>>>(x, xb, MROWS * D_MODEL / 4);
  k_tcvt<<<dim3(3 * D_MODEL / 32, D_MODEL / 32), dim3(256), 0, stream>>>(wqkv, wqkvT, D_MODEL, 3 * D_MODEL);
  k_tcvt<<<dim3(D_MODEL / 32, D_MODEL / 32), dim3(256), 0, stream>>>(wproj, wprojT, D_MODEL, D_MODEL);
  k_gemm_qkv<<<dim3(3 * D_MODEL / 128, MROWS / 128), dim3(256), 0, stream>>>(xb, wqkvT, bqkv, Qb, Kb, VTb);
  // 512 balanced blocks: (bh fast => XCD-pinned K/V, qt-pair p & 15-p per block)
  k_attn<<<dim3(NB * NH, 8), dim3(512), 0, stream>>>(Qb, Kb, VTb, Yb);
  k_gemm_proj<<<dim3(D_MODEL / 128, MROWS / 128), dim3(256), 0, stream>>>(Yb, wprojT, bproj, out);
}